// Round 2
// baseline (16156.149 us; speedup 1.0000x reference)
//
#include <hip/hip_runtime.h>
#include <hip/hip_bf16.h>

#define N_NODES 8000
#define N_EDGES 64000
#define NBATCH  64
#define NGRID   12
#define HIDC    128
#define EPB     16

__device__ __forceinline__ float gelu_f(float x) {
    return 0.5f * x * (1.0f + erff(x * 0.70710678118654752440f));
}

// ---------------- grid0 + per-batch rotated grids ----------------
__global__ void k_grid(const float* __restrict__ Q, float* __restrict__ grid0,
                       float* __restrict__ grid) {
    int t = threadIdx.x;
    __shared__ float g0[12][3];
    if (t < 12) {
        float fi = (float)t;
        float theta = 6.28318530717958647692f * fi / 1.61803398874989484820f;
        float z = 1.0f - (2.0f * fi + 1.0f) / 12.0f;
        float r = sqrtf(fmaxf(1.0f - z * z, 0.0f));
        g0[t][0] = r * cosf(theta);
        g0[t][1] = r * sinf(theta);
        g0[t][2] = z;
        grid0[t * 3 + 0] = g0[t][0];
        grid0[t * 3 + 1] = g0[t][1];
        grid0[t * 3 + 2] = g0[t][2];
    }
    __syncthreads();
    for (int idx = t; idx < NBATCH * 12 * 3; idx += blockDim.x) {
        int b = idx / 36, rmd = idx % 36, n = rmd / 3, i = rmd % 3;
        float acc = 0.f;
        #pragma unroll
        for (int j = 0; j < 3; ++j) acc += Q[b * 9 + i * 3 + j] * g0[n][j];
        grid[idx] = acc;
    }
}

// ---------------- kb_sh -> fk  (3,12,12,128) ----------------
__global__ __launch_bounds__(128) void k_kbsh(
    const float* __restrict__ grid0,
    const float* __restrict__ Wsh1, const float* __restrict__ bsh1,
    const float* __restrict__ Wsh2, const float* __restrict__ bsh2,
    const float* __restrict__ Wfk, float* __restrict__ fk) {
    int row = blockIdx.x;            // p*12+o
    int p = row / 12, o = row % 12, t = threadIdx.x;
    float tt = grid0[p*3]*grid0[o*3] + grid0[p*3+1]*grid0[o*3+1] + grid0[p*3+2]*grid0[o*3+2];
    float p1 = tt, p2 = tt * tt, p3 = p2 * tt;
    float h1 = gelu_f(p1 * Wsh1[t] + p2 * Wsh1[128 + t] + p3 * Wsh1[256 + t] + bsh1[t]);
    __shared__ float h1S[128];
    __shared__ float h2S[128];
    h1S[t] = h1;
    __syncthreads();
    float acc = bsh2[t];
    #pragma unroll 8
    for (int k = 0; k < 128; ++k) acc += h1S[k] * Wsh2[k * 128 + t];
    h2S[t] = gelu_f(acc);
    __syncthreads();
    for (int l = 0; l < 3; ++l) {
        float a = 0.f;
        #pragma unroll 8
        for (int k = 0; k < 128; ++k) a += h2S[k] * Wfk[l * 16384 + k * 128 + t];
        fk[l * 18432 + row * 128 + t] = a;
    }
}

// ---------------- node_grid + h0 = f @ Wemb ----------------
__global__ __launch_bounds__(128) void k_embed(
    const float* __restrict__ x, const float* __restrict__ vec,
    const int* __restrict__ batch, const float* __restrict__ grid,
    const float* __restrict__ Wemb, float* __restrict__ node_grid,
    float* __restrict__ h) {
    __shared__ float WembS[18 * 128];
    __shared__ float ngS[36];
    __shared__ float xS[16];
    __shared__ float vS[6];
    int n = blockIdx.x, t = threadIdx.x;
    for (int i = t; i < 18 * 128; i += 128) WembS[i] = Wemb[i];
    int b = batch[n];
    if (t < 36) { float g = grid[b * 36 + t]; ngS[t] = g; node_grid[n * 36 + t] = g; }
    if (t < 16) xS[t] = x[n * 16 + t];
    if (t >= 16 && t < 22) vS[t - 16] = vec[n * 6 + (t - 16)];
    __syncthreads();
    for (int g = 0; g < NGRID; ++g) {
        float g0 = ngS[g*3], g1 = ngS[g*3+1], g2 = ngS[g*3+2];
        float xv0 = vS[0]*g0 + vS[1]*g1 + vS[2]*g2;
        float xv1 = vS[3]*g0 + vS[4]*g1 + vS[5]*g2;
        float acc = xv0 * WembS[16*128 + t] + xv1 * WembS[17*128 + t];
        #pragma unroll
        for (int j = 0; j < 16; ++j) acc += xS[j] * WembS[j*128 + t];
        h[((size_t)n * NGRID + g) * HIDC + t] = acc;
    }
}

// ---------------- per-(edge,grid) invariants ----------------
__global__ __launch_bounds__(256) void k_attr(
    const float* __restrict__ pos, const float* __restrict__ ng,
    const int* __restrict__ send, const int* __restrict__ recv,
    float* __restrict__ attr) {
    int idx = blockIdx.x * 256 + threadIdx.x;
    if (idx >= N_EDGES * 12) return;
    int e = idx / 12, g = idx % 12;
    int s = send[e], r = recv[e];
    float rx = pos[s*3+0] - pos[r*3+0];
    float ry = pos[s*3+1] - pos[r*3+1];
    float rz = pos[s*3+2] - pos[r*3+2];
    const float* gr = ng + ((size_t)r * 12 + g) * 3;
    float g0 = gr[0], g1 = gr[1], g2 = gr[2];
    float iv1 = rx*g0 + ry*g1 + rz*g2;
    float wx = rx - iv1*g0, wy = ry - iv1*g1, wz = rz - iv1*g2;
    attr[(size_t)idx * 2 + 0] = iv1;
    attr[(size_t)idx * 2 + 1] = sqrtf(wx*wx + wy*wy + wz*wz);
}

// ---------------- per-layer fused: basis MLP + k + message + scatter ----------------
// 256 threads: lo half (t<128) computes h1 -> h2 (=kb) with Wsp2 column in regs;
// hi half computes k = kb @ Wk with Wk column in regs, multiplies h[send], atomics to agg.
// Double-buffered h2S pipelines the two halves across edges.
__global__ __launch_bounds__(256, 2) void k_msg_rc(
    const float* __restrict__ attr, const int* __restrict__ send,
    const int* __restrict__ recv,
    const float* __restrict__ Wsp1, const float* __restrict__ bsp1,
    const float* __restrict__ Wsp2, const float* __restrict__ bsp2,
    const float* __restrict__ Wk, const float* __restrict__ h,
    float* __restrict__ agg) {
    __shared__ float h1S[12][128];
    __shared__ float h2S[2][12][128];
    int t = threadIdx.x;
    int c = t & 127, half = t >> 7;
    float wm[128];
    if (half == 0) {
        #pragma unroll
        for (int k = 0; k < 128; ++k) wm[k] = Wsp2[k * 128 + c];
    } else {
        #pragma unroll
        for (int k = 0; k < 128; ++k) wm[k] = Wk[k * 128 + c];
    }
    // pre-combined polynomial weights (poly_features duplicates mixed terms)
    float w_a, w_b, w_aa, w_ab, w_bb, w_aaa, w_aab, w_abb, w_bbb, b1v, b2v;
    {
        float w1[14];
        #pragma unroll
        for (int j = 0; j < 14; ++j) w1[j] = Wsp1[j * 128 + c];
        w_a = w1[0]; w_b = w1[1];
        w_aa = w1[2]; w_ab = w1[3] + w1[4]; w_bb = w1[5];
        w_aaa = w1[6]; w_aab = w1[7] + w1[8] + w1[10];
        w_abb = w1[9] + w1[11] + w1[12]; w_bbb = w1[13];
        b1v = bsp1[c]; b2v = bsp2[c];
    }
    int e0 = blockIdx.x * EPB;
    for (int ee = 0; ee <= EPB; ++ee) {
        if (half == 0 && ee < EPB) {
            int e = e0 + ee;
            const float* ae = attr + (size_t)e * 24;
            for (int g = 0; g < 12; ++g) {
                float a = ae[g * 2], b = ae[g * 2 + 1];
                float aa = a * a, ab = a * b, bb = b * b;
                float acc = b1v + a * w_a + b * w_b
                          + aa * w_aa + ab * w_ab + bb * w_bb
                          + aa * a * w_aaa + aa * b * w_aab
                          + bb * a * w_abb + bb * b * w_bbb;
                h1S[g][c] = gelu_f(acc);
            }
        }
        __syncthreads();
        if (half == 0) {
            if (ee < EPB) {
                int wb = ee & 1;
                for (int g = 0; g < 12; ++g) {
                    float a0 = 0.f, a1 = 0.f, a2 = 0.f, a3 = 0.f;
                    #pragma unroll
                    for (int k = 0; k < 128; k += 4) {
                        a0 += h1S[g][k+0] * wm[k+0];
                        a1 += h1S[g][k+1] * wm[k+1];
                        a2 += h1S[g][k+2] * wm[k+2];
                        a3 += h1S[g][k+3] * wm[k+3];
                    }
                    h2S[wb][g][c] = gelu_f(b2v + (a0 + a1) + (a2 + a3));
                }
            }
        } else {
            if (ee > 0) {
                int e = e0 + ee - 1;
                int rb = (ee - 1) & 1;
                int s = send[e], r = recv[e];
                for (int g = 0; g < 12; ++g) {
                    float a0 = 0.f, a1 = 0.f, a2 = 0.f, a3 = 0.f;
                    #pragma unroll
                    for (int k = 0; k < 128; k += 4) {
                        a0 += h2S[rb][g][k+0] * wm[k+0];
                        a1 += h2S[rb][g][k+1] * wm[k+1];
                        a2 += h2S[rb][g][k+2] * wm[k+2];
                        a3 += h2S[rb][g][k+3] * wm[k+3];
                    }
                    float kv = (a0 + a1) + (a2 + a3);
                    float m = h[((size_t)s * 12 + g) * 128 + c] * kv;
                    atomicAdd(&agg[((size_t)r * 12 + g) * 128 + c], m);
                }
            }
        }
        __syncthreads();
    }
}

// ---------------- per-layer per-node: conv + LN + MLP + residual + readout ----------------
__global__ __launch_bounds__(128) void k_node(
    const float* __restrict__ agg, const float* __restrict__ fk,
    const float* __restrict__ bconv, const float* __restrict__ ln_g,
    const float* __restrict__ ln_b,
    const float* __restrict__ W1, const float* __restrict__ b1,
    const float* __restrict__ W2, const float* __restrict__ b2,
    const float* __restrict__ Wro, const float* __restrict__ bro,
    float* __restrict__ h, float* __restrict__ readout) {
    __shared__ float A[12 * 128];
    __shared__ float H[12 * 128];
    __shared__ float HIDS[12 * 512];
    __shared__ float red[12][2][2];
    int n = blockIdx.x, t = threadIdx.x;
    int lane = t & 63, wid = t >> 6;
    for (int i = t; i < 1536; i += 128) A[i] = agg[(size_t)n * 1536 + i];
    __syncthreads();
    float x2v[12];
    float bcv = bconv[t];
    #pragma unroll
    for (int p = 0; p < 12; ++p) {
        float acc = 0.f;
        #pragma unroll
        for (int o = 0; o < 12; ++o) acc += A[o * 128 + t] * fk[(p * 12 + o) * 128 + t];
        x2v[p] = acc * (1.0f / 12.0f) + bcv;
    }
    #pragma unroll
    for (int p = 0; p < 12; ++p) {
        float s = x2v[p], s2 = x2v[p] * x2v[p];
        for (int off = 32; off > 0; off >>= 1) {
            s += __shfl_down(s, off);
            s2 += __shfl_down(s2, off);
        }
        if (lane == 0) { red[p][wid][0] = s; red[p][wid][1] = s2; }
    }
    __syncthreads();
    float gv = ln_g[t], bv = ln_b[t];
    #pragma unroll
    for (int p = 0; p < 12; ++p) {
        float mu = (red[p][0][0] + red[p][1][0]) * (1.0f / 128.0f);
        float var = (red[p][0][1] + red[p][1][1]) * (1.0f / 128.0f) - mu * mu;
        H[p * 128 + t] = (x2v[p] - mu) * rsqrtf(var + 1e-5f) * gv + bv;
    }
    __syncthreads();
    for (int q = 0; q < 4; ++q) {
        int j = t + q * 128;
        float acc[12];
        float bj = b1[j];
        #pragma unroll
        for (int p = 0; p < 12; ++p) acc[p] = bj;
        for (int k = 0; k < 128; ++k) {
            float wv = W1[k * 512 + j];
            #pragma unroll
            for (int p = 0; p < 12; ++p) acc[p] += H[p * 128 + k] * wv;
        }
        #pragma unroll
        for (int p = 0; p < 12; ++p) HIDS[p * 512 + j] = gelu_f(acc[p]);
    }
    __syncthreads();
    float acc2[12];
    float b2v = b2[t];
    #pragma unroll
    for (int p = 0; p < 12; ++p) acc2[p] = b2v;
    for (int k = 0; k < 512; ++k) {
        float wv = W2[k * 128 + t];
        #pragma unroll
        for (int p = 0; p < 12; ++p) acc2[p] += HIDS[p * 512 + k] * wv;
    }
    #pragma unroll
    for (int p = 0; p < 12; ++p) {
        size_t hi = (size_t)n * 1536 + p * 128 + t;
        float hv = h[hi] + acc2[p];
        h[hi] = hv;
        H[p * 128 + t] = hv;
    }
    __syncthreads();
    if (t < 108) {
        int p = t / 9, j = t % 9;
        float acc = 0.f;
        for (int cc = 0; cc < 128; ++cc) acc += H[p * 128 + cc] * Wro[cc * 9 + j];
        readout[((size_t)n * 12 + p) * 9 + j] += (acc + bro[j]) * (1.0f / 3.0f);
    }
}

// ---------------- final pooling ----------------
__global__ __launch_bounds__(128) void k_out(
    const float* __restrict__ readout, const float* __restrict__ node_grid,
    const int* __restrict__ batch, float* __restrict__ out) {
    int n = blockIdx.x * 128 + threadIdx.x;
    if (n >= N_NODES) return;
    int b = batch[n];
    const float* ro = readout + (size_t)n * 108;
    float ss[8] = {0, 0, 0, 0, 0, 0, 0, 0};
    float v0 = 0.f, v1 = 0.f, v2 = 0.f;
    for (int p = 0; p < 12; ++p) {
        #pragma unroll
        for (int j = 0; j < 8; ++j) ss[j] += ro[p * 9 + j];
        float rv = ro[p * 9 + 8];
        v0 += rv * node_grid[n * 36 + p * 3 + 0];
        v1 += rv * node_grid[n * 36 + p * 3 + 1];
        v2 += rv * node_grid[n * 36 + p * 3 + 2];
    }
    #pragma unroll
    for (int j = 0; j < 8; ++j) atomicAdd(&out[b * 8 + j], ss[j] * (1.0f / 12.0f));
    atomicAdd(&out[512 + b * 3 + 0], v0 * (1.0f / 12.0f));
    atomicAdd(&out[512 + b * 3 + 1], v1 * (1.0f / 12.0f));
    atomicAdd(&out[512 + b * 3 + 2], v2 * (1.0f / 12.0f));
}

extern "C" void kernel_launch(void* const* d_in, const int* in_sizes, int n_in,
                              void* d_out, int out_size, void* d_ws, size_t ws_size,
                              hipStream_t stream) {
    const float* x    = (const float*)d_in[0];
    const float* vec  = (const float*)d_in[1];
    const float* pos  = (const float*)d_in[2];
    const float* Q    = (const float*)d_in[3];
    const float* Wsp1 = (const float*)d_in[4];
    const float* bsp1 = (const float*)d_in[5];
    const float* Wsp2 = (const float*)d_in[6];
    const float* bsp2 = (const float*)d_in[7];
    const float* Wsh1 = (const float*)d_in[8];
    const float* bsh1 = (const float*)d_in[9];
    const float* Wsh2 = (const float*)d_in[10];
    const float* bsh2 = (const float*)d_in[11];
    const float* Wemb = (const float*)d_in[12];
    const float* Wk   = (const float*)d_in[13];
    const float* Wfk  = (const float*)d_in[14];
    const float* bconv= (const float*)d_in[15];
    const float* ln_g = (const float*)d_in[16];
    const float* ln_b = (const float*)d_in[17];
    const float* W1   = (const float*)d_in[18];
    const float* b1   = (const float*)d_in[19];
    const float* W2   = (const float*)d_in[20];
    const float* b2   = (const float*)d_in[21];
    const float* Wro  = (const float*)d_in[22];
    const float* bro  = (const float*)d_in[23];
    const int* ei     = (const int*)d_in[24];
    const int* batch  = (const int*)d_in[25];
    const int* send = ei;
    const int* recv = ei + N_EDGES;

    // workspace layout (floats) — total 27,321,728 floats = 109.3 MB
    float* ws    = (float*)d_ws;
    float* grid0 = ws;                    // 64
    float* grid  = ws + 64;               // 2304
    float* fk    = ws + 2432;             // 55296
    float* ng    = ws + 57728;            // 288000
    float* ro    = ws + 345728;           // 864000
    float* attr  = ws + 1209728;          // 1536000
    float* agg   = ws + 2745728;          // 12288000
    float* h     = ws + 15033728;         // 12288000
    const size_t NEED = 27321728ull * 4ull;
    if (ws_size < NEED) return;  // fail cleanly (absmax=ref max) instead of faulting

    hipMemsetAsync(d_out, 0, sizeof(float) * (size_t)out_size, stream);
    hipMemsetAsync(ro, 0, sizeof(float) * 864000, stream);

    k_grid<<<1, 256, 0, stream>>>(Q, grid0, grid);
    k_kbsh<<<144, 128, 0, stream>>>(grid0, Wsh1, bsh1, Wsh2, bsh2, Wfk, fk);
    k_embed<<<N_NODES, 128, 0, stream>>>(x, vec, batch, grid, Wemb, ng, h);
    k_attr<<<(N_EDGES * 12 + 255) / 256, 256, 0, stream>>>(pos, ng, send, recv, attr);

    for (int l = 0; l < 3; ++l) {
        hipMemsetAsync(agg, 0, sizeof(float) * 12288000, stream);
        k_msg_rc<<<N_EDGES / EPB, 256, 0, stream>>>(attr, send, recv,
            Wsp1, bsp1, Wsp2, bsp2, Wk + l * 16384, h, agg);
        k_node<<<N_NODES, 128, 0, stream>>>(agg, fk + l * 18432, bconv + l * 128,
            ln_g + l * 128, ln_b + l * 128, W1 + l * 65536, b1 + l * 512,
            W2 + l * 65536, b2 + l * 128, Wro + l * 1152, bro + l * 9, h, ro);
    }
    k_out<<<(N_NODES + 127) / 128, 128, 0, stream>>>(ro, ng, batch, (float*)d_out);
}

// Round 3
// 5592.705 us; speedup vs baseline: 2.8888x; 2.8888x over previous
//
#include <hip/hip_runtime.h>
#include <hip/hip_bf16.h>

#define N_NODES 8000
#define N_EDGES 64000
#define NBATCH  64
#define NGRID   12
#define HIDC    128

typedef __bf16 bf16x8 __attribute__((ext_vector_type(8)));
typedef float  f32x4  __attribute__((ext_vector_type(4)));

__device__ __forceinline__ float gelu_f(float x) {
    return 0.5f * x * (1.0f + erff(x * 0.70710678118654752440f));
}

// ---------------- grid0 + per-batch rotated grids ----------------
__global__ void k_grid(const float* __restrict__ Q, float* __restrict__ grid0,
                       float* __restrict__ grid) {
    int t = threadIdx.x;
    __shared__ float g0[12][3];
    if (t < 12) {
        float fi = (float)t;
        float theta = 6.28318530717958647692f * fi / 1.61803398874989484820f;
        float z = 1.0f - (2.0f * fi + 1.0f) / 12.0f;
        float r = sqrtf(fmaxf(1.0f - z * z, 0.0f));
        g0[t][0] = r * cosf(theta);
        g0[t][1] = r * sinf(theta);
        g0[t][2] = z;
        grid0[t * 3 + 0] = g0[t][0];
        grid0[t * 3 + 1] = g0[t][1];
        grid0[t * 3 + 2] = g0[t][2];
    }
    __syncthreads();
    for (int idx = t; idx < NBATCH * 12 * 3; idx += blockDim.x) {
        int b = idx / 36, rmd = idx % 36, n = rmd / 3, i = rmd % 3;
        float acc = 0.f;
        #pragma unroll
        for (int j = 0; j < 3; ++j) acc += Q[b * 9 + i * 3 + j] * g0[n][j];
        grid[idx] = acc;
    }
}

// ---------------- kb_sh -> fk  (3,12,12,128) ----------------
__global__ __launch_bounds__(128) void k_kbsh(
    const float* __restrict__ grid0,
    const float* __restrict__ Wsh1, const float* __restrict__ bsh1,
    const float* __restrict__ Wsh2, const float* __restrict__ bsh2,
    const float* __restrict__ Wfk, float* __restrict__ fk) {
    int row = blockIdx.x;            // p*12+o
    int p = row / 12, o = row % 12, t = threadIdx.x;
    float tt = grid0[p*3]*grid0[o*3] + grid0[p*3+1]*grid0[o*3+1] + grid0[p*3+2]*grid0[o*3+2];
    float p1 = tt, p2 = tt * tt, p3 = p2 * tt;
    float h1 = gelu_f(p1 * Wsh1[t] + p2 * Wsh1[128 + t] + p3 * Wsh1[256 + t] + bsh1[t]);
    __shared__ float h1S[128];
    __shared__ float h2S[128];
    h1S[t] = h1;
    __syncthreads();
    float acc = bsh2[t];
    #pragma unroll 8
    for (int k = 0; k < 128; ++k) acc += h1S[k] * Wsh2[k * 128 + t];
    h2S[t] = gelu_f(acc);
    __syncthreads();
    for (int l = 0; l < 3; ++l) {
        float a = 0.f;
        #pragma unroll 8
        for (int k = 0; k < 128; ++k) a += h2S[k] * Wfk[l * 16384 + k * 128 + t];
        fk[l * 18432 + row * 128 + t] = a;
    }
}

// ---------------- node_grid + h0 = f @ Wemb ----------------
__global__ __launch_bounds__(128) void k_embed(
    const float* __restrict__ x, const float* __restrict__ vec,
    const int* __restrict__ batch, const float* __restrict__ grid,
    const float* __restrict__ Wemb, float* __restrict__ node_grid,
    float* __restrict__ h) {
    __shared__ float WembS[18 * 128];
    __shared__ float ngS[36];
    __shared__ float xS[16];
    __shared__ float vS[6];
    int n = blockIdx.x, t = threadIdx.x;
    for (int i = t; i < 18 * 128; i += 128) WembS[i] = Wemb[i];
    int b = batch[n];
    if (t < 36) { float g = grid[b * 36 + t]; ngS[t] = g; node_grid[n * 36 + t] = g; }
    if (t < 16) xS[t] = x[n * 16 + t];
    if (t >= 16 && t < 22) vS[t - 16] = vec[n * 6 + (t - 16)];
    __syncthreads();
    for (int g = 0; g < NGRID; ++g) {
        float g0 = ngS[g*3], g1 = ngS[g*3+1], g2 = ngS[g*3+2];
        float xv0 = vS[0]*g0 + vS[1]*g1 + vS[2]*g2;
        float xv1 = vS[3]*g0 + vS[4]*g1 + vS[5]*g2;
        float acc = xv0 * WembS[16*128 + t] + xv1 * WembS[17*128 + t];
        #pragma unroll
        for (int j = 0; j < 16; ++j) acc += xS[j] * WembS[j*128 + t];
        h[((size_t)n * NGRID + g) * HIDC + t] = acc;
    }
}

// ---------------- per-(edge,grid) invariants ----------------
__global__ __launch_bounds__(256) void k_attr(
    const float* __restrict__ pos, const float* __restrict__ ng,
    const int* __restrict__ send, const int* __restrict__ recv,
    float* __restrict__ attr) {
    int idx = blockIdx.x * 256 + threadIdx.x;
    if (idx >= N_EDGES * 12) return;
    int e = idx / 12, g = idx % 12;
    int s = send[e], r = recv[e];
    float rx = pos[s*3+0] - pos[r*3+0];
    float ry = pos[s*3+1] - pos[r*3+1];
    float rz = pos[s*3+2] - pos[r*3+2];
    const float* gr = ng + ((size_t)r * 12 + g) * 3;
    float g0 = gr[0], g1 = gr[1], g2 = gr[2];
    float iv1 = rx*g0 + ry*g1 + rz*g2;
    float wx = rx - iv1*g0, wy = ry - iv1*g1, wz = rz - iv1*g2;
    attr[(size_t)idx * 2 + 0] = iv1;
    attr[(size_t)idx * 2 + 1] = sqrtf(wx*wx + wy*wy + wz*wz);
}

// ---------------- transpose + bf16-convert weights: WT[0]=Wsp2T, WT[1..3]=WkT[l] ----------------
__global__ __launch_bounds__(256) void k_prepw(const float* __restrict__ Wsp2,
                                               const float* __restrict__ Wk,
                                               __bf16* __restrict__ WT) {
    int i = blockIdx.x * 256 + threadIdx.x;
    if (i >= 4 * 16384) return;
    int buf = i >> 14, r = i & 16383;
    int n = r >> 7, k = r & 127;
    float v = (buf == 0) ? Wsp2[k * 128 + n] : Wk[(buf - 1) * 16384 + k * 128 + n];
    WT[i] = (__bf16)v;
}

// ---------------- per-layer fused edge kernel (MFMA) ----------------
// Tile = 16 edges -> 192 rows of (edge,grid). h1 (bf16) in LDS (padded rows),
// two 192x128x128 GEMMs with B-fragments read from global bf16 transposed
// weights (L1/L2-resident). Rows are partitioned per wave -> kb writeback is
// wave-local, so only 2 barriers per tile. Epilogue: gather h[send], atomic agg.
__global__ __launch_bounds__(256, 2) void k_edge_mfma(
    const float* __restrict__ attr, const int* __restrict__ send,
    const int* __restrict__ recv,
    const __bf16* __restrict__ W2T,   // Wsp2 transposed [n*128+k]
    const __bf16* __restrict__ WkTl,  // Wk[l] transposed [n*128+k]
    const float* __restrict__ Wsp1, const float* __restrict__ bsp1,
    const float* __restrict__ bsp2,
    const float* __restrict__ h, float* __restrict__ agg) {
    __shared__ __align__(16) __bf16 A_lds[192 * 136];
    __shared__ int sendS[16], recvS[16];
    int t = threadIdx.x;
    int lane = t & 63, w = t >> 6;
    int l15 = lane & 15, quad = lane >> 4;

    // per-thread poly weights for column c (combined poly_features duplicates)
    int c = t & 127, rh = t >> 7;
    float w_a, w_b, w_aa, w_ab, w_bb, w_aaa, w_aab, w_abb, w_bbb, b1v;
    {
        float w1[14];
        #pragma unroll
        for (int j = 0; j < 14; ++j) w1[j] = Wsp1[j * 128 + c];
        w_a = w1[0]; w_b = w1[1];
        w_aa = w1[2]; w_ab = w1[3] + w1[4]; w_bb = w1[5];
        w_aaa = w1[6]; w_aab = w1[7] + w1[8] + w1[10];
        w_abb = w1[9] + w1[11] + w1[12]; w_bbb = w1[13];
        b1v = bsp1[c];
    }
    float b2v[8];
    #pragma unroll
    for (int nt = 0; nt < 8; ++nt) b2v[nt] = bsp2[nt * 16 + l15];

    for (int tile = 0; tile < 4; ++tile) {
        int e0 = (blockIdx.x * 4 + tile) * 16;
        __syncthreads();                       // prev tile fully consumed
        if (t < 16) sendS[t] = send[e0 + t];
        else if (t < 32) recvS[t - 16] = recv[e0 + t - 16];
        // poly -> h1 (bf16) ; thread owns column c, half the rows
        const float2* ap = (const float2*)attr + (size_t)e0 * 12 + rh * 96;
        for (int r = 0; r < 96; ++r) {
            float2 abv = ap[r];
            float a = abv.x, b = abv.y;
            float aa = a * a, ab = a * b, bb = b * b;
            float v = b1v + a * w_a + b * w_b + aa * w_aa + ab * w_ab + bb * w_bb
                    + aa * a * w_aaa + aa * b * w_aab + bb * a * w_abb + bb * b * w_bbb;
            A_lds[(rh * 96 + r) * 136 + c] = (__bf16)gelu_f(v);
        }
        __syncthreads();
        int rb = w * 48;                       // wave-owned rows [rb, rb+48)
        f32x4 acc[3][8];
        #pragma unroll
        for (int mt = 0; mt < 3; ++mt)
            #pragma unroll
            for (int nt = 0; nt < 8; ++nt) acc[mt][nt] = (f32x4){0.f, 0.f, 0.f, 0.f};
        // GEMM1: kb_pre = h1 @ Wsp2
        #pragma unroll
        for (int ks = 0; ks < 4; ++ks) {
            bf16x8 bfr[8];
            #pragma unroll
            for (int nt = 0; nt < 8; ++nt)
                bfr[nt] = *(const bf16x8*)(W2T + (nt * 16 + l15) * 128 + ks * 32 + quad * 8);
            #pragma unroll
            for (int mt = 0; mt < 3; ++mt) {
                bf16x8 af = *(const bf16x8*)(A_lds + (rb + mt * 16 + l15) * 136 + ks * 32 + quad * 8);
                #pragma unroll
                for (int nt = 0; nt < 8; ++nt)
                    acc[mt][nt] = __builtin_amdgcn_mfma_f32_16x16x32_bf16(af, bfr[nt], acc[mt][nt], 0, 0, 0);
            }
        }
        // bias + gelu -> kb, write back into own rows (wave-local, no barrier)
        #pragma unroll
        for (int mt = 0; mt < 3; ++mt)
            #pragma unroll
            for (int nt = 0; nt < 8; ++nt)
                #pragma unroll
                for (int rg = 0; rg < 4; ++rg) {
                    int row = rb + mt * 16 + quad * 4 + rg;
                    A_lds[row * 136 + nt * 16 + l15] = (__bf16)gelu_f(acc[mt][nt][rg] + b2v[nt]);
                }
        #pragma unroll
        for (int mt = 0; mt < 3; ++mt)
            #pragma unroll
            for (int nt = 0; nt < 8; ++nt) acc[mt][nt] = (f32x4){0.f, 0.f, 0.f, 0.f};
        // GEMM2: k = kb @ Wk[l]
        #pragma unroll
        for (int ks = 0; ks < 4; ++ks) {
            bf16x8 bfr[8];
            #pragma unroll
            for (int nt = 0; nt < 8; ++nt)
                bfr[nt] = *(const bf16x8*)(WkTl + (nt * 16 + l15) * 128 + ks * 32 + quad * 8);
            #pragma unroll
            for (int mt = 0; mt < 3; ++mt) {
                bf16x8 af = *(const bf16x8*)(A_lds + (rb + mt * 16 + l15) * 136 + ks * 32 + quad * 8);
                #pragma unroll
                for (int nt = 0; nt < 8; ++nt)
                    acc[mt][nt] = __builtin_amdgcn_mfma_f32_16x16x32_bf16(af, bfr[nt], acc[mt][nt], 0, 0, 0);
            }
        }
        // epilogue: msg = h[send] * k ; atomic scatter to agg[recv]
        #pragma unroll
        for (int mt = 0; mt < 3; ++mt) {
            #pragma unroll
            for (int rg = 0; rg < 4; ++rg) {
                int row = rb + mt * 16 + quad * 4 + rg;
                int el = row / 12;
                int g  = row - el * 12;
                size_t hbase = ((size_t)sendS[el] * 12 + g) * 128;
                size_t abase = ((size_t)recvS[el] * 12 + g) * 128;
                #pragma unroll
                for (int nt = 0; nt < 8; ++nt) {
                    int cc = nt * 16 + l15;
                    float hv = h[hbase + cc];
                    atomicAdd(&agg[abase + cc], acc[mt][nt][rg] * hv);
                }
            }
        }
    }
}

// ---------------- per-layer per-node: conv + LN + MLP + residual + readout ----------------
__global__ __launch_bounds__(128) void k_node(
    const float* __restrict__ agg, const float* __restrict__ fk,
    const float* __restrict__ bconv, const float* __restrict__ ln_g,
    const float* __restrict__ ln_b,
    const float* __restrict__ W1, const float* __restrict__ b1,
    const float* __restrict__ W2, const float* __restrict__ b2,
    const float* __restrict__ Wro, const float* __restrict__ bro,
    float* __restrict__ h, float* __restrict__ readout) {
    __shared__ __align__(16) float A[12 * 128];
    __shared__ __align__(16) float H[12 * 128];
    __shared__ __align__(16) float HIDS[12 * 512];
    __shared__ float red[12][2][2];
    int n = blockIdx.x, t = threadIdx.x;
    int lane = t & 63, wid = t >> 6;
    for (int i = t; i < 1536; i += 128) A[i] = agg[(size_t)n * 1536 + i];
    __syncthreads();
    float x2v[12];
    float bcv = bconv[t];
    #pragma unroll
    for (int p = 0; p < 12; ++p) {
        float acc = 0.f;
        #pragma unroll
        for (int o = 0; o < 12; ++o) acc += A[o * 128 + t] * fk[(p * 12 + o) * 128 + t];
        x2v[p] = acc * (1.0f / 12.0f) + bcv;
    }
    #pragma unroll
    for (int p = 0; p < 12; ++p) {
        float s = x2v[p], s2 = x2v[p] * x2v[p];
        for (int off = 32; off > 0; off >>= 1) {
            s += __shfl_down(s, off);
            s2 += __shfl_down(s2, off);
        }
        if (lane == 0) { red[p][wid][0] = s; red[p][wid][1] = s2; }
    }
    __syncthreads();
    float gv = ln_g[t], bv = ln_b[t];
    #pragma unroll
    for (int p = 0; p < 12; ++p) {
        float mu = (red[p][0][0] + red[p][1][0]) * (1.0f / 128.0f);
        float var = (red[p][0][1] + red[p][1][1]) * (1.0f / 128.0f) - mu * mu;
        H[p * 128 + t] = (x2v[p] - mu) * rsqrtf(var + 1e-5f) * gv + bv;
    }
    __syncthreads();
    for (int q = 0; q < 4; ++q) {
        int j = t + q * 128;
        float acc[12];
        float bj = b1[j];
        #pragma unroll
        for (int p = 0; p < 12; ++p) acc[p] = bj;
        for (int k = 0; k < 128; k += 4) {
            float wv0 = W1[(k+0) * 512 + j], wv1 = W1[(k+1) * 512 + j];
            float wv2 = W1[(k+2) * 512 + j], wv3 = W1[(k+3) * 512 + j];
            #pragma unroll
            for (int p = 0; p < 12; ++p) {
                float4 hv = *(const float4*)&H[p * 128 + k];
                acc[p] += hv.x * wv0 + hv.y * wv1 + hv.z * wv2 + hv.w * wv3;
            }
        }
        #pragma unroll
        for (int p = 0; p < 12; ++p) HIDS[p * 512 + j] = gelu_f(acc[p]);
    }
    __syncthreads();
    float acc2[12];
    float b2v = b2[t];
    #pragma unroll
    for (int p = 0; p < 12; ++p) acc2[p] = b2v;
    for (int k = 0; k < 512; k += 4) {
        float wv0 = W2[(k+0) * 128 + t], wv1 = W2[(k+1) * 128 + t];
        float wv2 = W2[(k+2) * 128 + t], wv3 = W2[(k+3) * 128 + t];
        #pragma unroll
        for (int p = 0; p < 12; ++p) {
            float4 hv = *(const float4*)&HIDS[p * 512 + k];
            acc2[p] += hv.x * wv0 + hv.y * wv1 + hv.z * wv2 + hv.w * wv3;
        }
    }
    #pragma unroll
    for (int p = 0; p < 12; ++p) {
        size_t hi = (size_t)n * 1536 + p * 128 + t;
        float hv = h[hi] + acc2[p];
        h[hi] = hv;
        H[p * 128 + t] = hv;
    }
    __syncthreads();
    if (t < 108) {
        int p = t / 9, j = t % 9;
        float acc = 0.f;
        for (int cc = 0; cc < 128; ++cc) acc += H[p * 128 + cc] * Wro[cc * 9 + j];
        readout[((size_t)n * 12 + p) * 9 + j] += (acc + bro[j]) * (1.0f / 3.0f);
    }
}

// ---------------- final pooling ----------------
__global__ __launch_bounds__(128) void k_out(
    const float* __restrict__ readout, const float* __restrict__ node_grid,
    const int* __restrict__ batch, float* __restrict__ out) {
    int n = blockIdx.x * 128 + threadIdx.x;
    if (n >= N_NODES) return;
    int b = batch[n];
    const float* ro = readout + (size_t)n * 108;
    float ss[8] = {0, 0, 0, 0, 0, 0, 0, 0};
    float v0 = 0.f, v1 = 0.f, v2 = 0.f;
    for (int p = 0; p < 12; ++p) {
        #pragma unroll
        for (int j = 0; j < 8; ++j) ss[j] += ro[p * 9 + j];
        float rv = ro[p * 9 + 8];
        v0 += rv * node_grid[n * 36 + p * 3 + 0];
        v1 += rv * node_grid[n * 36 + p * 3 + 1];
        v2 += rv * node_grid[n * 36 + p * 3 + 2];
    }
    #pragma unroll
    for (int j = 0; j < 8; ++j) atomicAdd(&out[b * 8 + j], ss[j] * (1.0f / 12.0f));
    atomicAdd(&out[512 + b * 3 + 0], v0 * (1.0f / 12.0f));
    atomicAdd(&out[512 + b * 3 + 1], v1 * (1.0f / 12.0f));
    atomicAdd(&out[512 + b * 3 + 2], v2 * (1.0f / 12.0f));
}

extern "C" void kernel_launch(void* const* d_in, const int* in_sizes, int n_in,
                              void* d_out, int out_size, void* d_ws, size_t ws_size,
                              hipStream_t stream) {
    const float* x    = (const float*)d_in[0];
    const float* vec  = (const float*)d_in[1];
    const float* pos  = (const float*)d_in[2];
    const float* Q    = (const float*)d_in[3];
    const float* Wsp1 = (const float*)d_in[4];
    const float* bsp1 = (const float*)d_in[5];
    const float* Wsp2 = (const float*)d_in[6];
    const float* bsp2 = (const float*)d_in[7];
    const float* Wsh1 = (const float*)d_in[8];
    const float* bsh1 = (const float*)d_in[9];
    const float* Wsh2 = (const float*)d_in[10];
    const float* bsh2 = (const float*)d_in[11];
    const float* Wemb = (const float*)d_in[12];
    const float* Wk   = (const float*)d_in[13];
    const float* Wfk  = (const float*)d_in[14];
    const float* bconv= (const float*)d_in[15];
    const float* ln_g = (const float*)d_in[16];
    const float* ln_b = (const float*)d_in[17];
    const float* W1   = (const float*)d_in[18];
    const float* b1   = (const float*)d_in[19];
    const float* W2   = (const float*)d_in[20];
    const float* b2   = (const float*)d_in[21];
    const float* Wro  = (const float*)d_in[22];
    const float* bro  = (const float*)d_in[23];
    const int* ei     = (const int*)d_in[24];
    const int* batch  = (const int*)d_in[25];
    const int* send = ei;
    const int* recv = ei + N_EDGES;

    // workspace layout (floats) — total 27,354,496 floats = 109.4 MB
    float* ws    = (float*)d_ws;
    float* grid0 = ws;                    // 64
    float* grid  = ws + 64;               // 2304
    float* fk    = ws + 2432;             // 55296
    float* ng    = ws + 57728;            // 288000
    float* ro    = ws + 345728;           // 864000
    float* attr  = ws + 1209728;          // 1536000
    float* agg   = ws + 2745728;          // 12288000
    float* h     = ws + 15033728;         // 12288000
    __bf16* WT   = (__bf16*)(ws + 27321728); // 65536 bf16 = 32768 floats
    const size_t NEED = 27354496ull * 4ull;
    if (ws_size < NEED) return;

    hipMemsetAsync(d_out, 0, sizeof(float) * (size_t)out_size, stream);
    hipMemsetAsync(ro, 0, sizeof(float) * 864000, stream);

    k_grid<<<1, 256, 0, stream>>>(Q, grid0, grid);
    k_kbsh<<<144, 128, 0, stream>>>(grid0, Wsh1, bsh1, Wsh2, bsh2, Wfk, fk);
    k_embed<<<N_NODES, 128, 0, stream>>>(x, vec, batch, grid, Wemb, ng, h);
    k_attr<<<(N_EDGES * 12 + 255) / 256, 256, 0, stream>>>(pos, ng, send, recv, attr);
    k_prepw<<<256, 256, 0, stream>>>(Wsp2, Wk, WT);

    for (int l = 0; l < 3; ++l) {
        hipMemsetAsync(agg, 0, sizeof(float) * 12288000, stream);
        k_edge_mfma<<<1000, 256, 0, stream>>>(attr, send, recv,
            WT, WT + (1 + l) * 16384, Wsp1, bsp1, bsp2, h, agg);
        k_node<<<N_NODES, 128, 0, stream>>>(agg, fk + l * 18432, bconv + l * 128,
            ln_g + l * 128, ln_b + l * 128, W1 + l * 65536, b1 + l * 512,
            W2 + l * 65536, b2 + l * 128, Wro + l * 1152, bro + l * 9, h, ro);
    }
    k_out<<<(N_NODES + 127) / 128, 128, 0, stream>>>(ro, ng, batch, (float*)d_out);
}